// Round 10
// baseline (451.500 us; speedup 1.0000x reference)
//
#include <hip/hip_runtime.h>

// DeepSNNController: 3-layer LIF SNN, T=100, B=4096, 9 -> 96 -> 96 -> 48.
//
// R18 = R17 (TC=2 time-chunked, wave-autonomous, zero barriers; 293us,
// absmax=0) with the fma stream PACKED: v_pk_fma_f32 does the two batches'
// chains in one instruction. R17 post-mortem: wall 7.0k cyc/t/CU with LDS
// ~3.4k (50% util) and VALU ~2.8k/SIMD (~40% real issue; derived VALUBusy
// 90% is the gfx94x formula over-counting 2x) -> latency-bound at 2
// waves/SIMD. Occupancy can't rise (weights replicated per block, 60KB+
// blocks never co-reside, R15). Lever: per-wave instruction count + chain
// depth. fma is the largest VALU stream (432/t/lane of ~700): the two
// batches of each (tp,s) accumulator are independent chains in lockstep with
// the same weight & j-order -> pack as v2f. Spike pair {sb0(j), sb1(j)} is
// built directly by the two byte-cvts (adjacent halves, no movs); weight
// splat folds into VOP3P op_sel (worst case 1 mov/scalar, still net win).
// fma 432 -> 216 pk; VALU ~700 -> ~500/t/lane; chains half as many insts.
//
// Exactness (absmax must stay 0): v_pk_fma_f32 components are IEEE f32 fma.
// Each (tp, s, batch) chain keeps the exact R14/R16/R17 j-ascending order
// (jc outer asc; within jc: wA j=8jc..+3 then wB j=8jc+4..+7); packing only
// fuses two INDEPENDENT chains per instruction -> identical bits per chain.
// Combine (c0+c1)+(c2+c3) via quad-perm DPP exchange-adds on the extracted
// halves; K=9 L1 tail-first r0=(q8+q0)+q4 verbatim; LIF pinned
// mn=((0.92*mp)+(dot+b))-reset, t-ascending per membrane chain. Products
// exact (spikes in {0,1}). Spike-buffer aliasing scheme = R16/R17 (verified).
//
// Structure (unchanged from R17): 8 waves x 2 batches, grid 256 = 1
// block/CU = 2 waves/SIMD; weights chunk-major 16B cells (measured
// conflict-free); fences lgkmcnt-only; x loads / out stores stay in flight.

constexpr int T_STEPS = 100;
constexpr int BATCH   = 4096;
constexpr int D_INP   = 9;
constexpr int H       = 96;
constexpr int H3      = 48;
constexpr int WAVES   = 8;
constexpr int BPW     = 2;               // batches per wave
constexpr int NB      = WAVES * BPW;     // 16 batches per block
constexpr int BLOCK   = WAVES * 64;      // 512 threads
constexpr int NBLK    = BATCH / NB;      // 256 blocks = 1 per CU
constexpr int TC      = 2;               // timesteps per weight sweep

typedef float v2f __attribute__((ext_vector_type(2)));

__device__ __forceinline__ v2f splat2(float w) { return (v2f){w, w}; }

__device__ __forceinline__ float lif_step(float sum, float bias, float& m) {
    const float cur   = __fadd_rn(sum, bias);
    const float mp    = m;
    const float reset = (mp > 1.0f) ? 1.0f : 0.0f;
    const float mn    = __fsub_rn(__fadd_rn(__fmul_rn(0.92f, mp), cur), reset);
    m = mn;
    return mn;
}

#if defined(__has_builtin)
#if __has_builtin(__builtin_amdgcn_mov_dpp)
#define SNN_HAS_DPP 1
#endif
#endif

// Quad exchange-and-add. CTRL=0xB1: quad_perm [1,0,3,2] (xor 1);
// CTRL=0x4E: quad_perm [2,3,0,1] (xor 2).
template <int CTRL>
__device__ __forceinline__ float xadd(float c) {
#ifdef SNN_HAS_DPP
    const int o = __builtin_amdgcn_mov_dpp(__float_as_int(c), CTRL, 0xF, 0xF, false);
    return __fadd_rn(c, __int_as_float(o));
#else
    return __fadd_rn(c, __shfl_xor(c, (CTRL == 0xB1) ? 1 : 2, 64));
#endif
}

// lanes r=0..3 hold P7 residue partials c_r; returns (c0+c1)+(c2+c3) in ALL lanes.
__device__ __forceinline__ float quad_red(float c) {
    return xadd<0x4E>(xadd<0xB1>(c));
}

// dword = ushorts {j0, j0+1}: bytes [b0(j0), b1(j0), b0(j0+1), b1(j0+1)].
// Each v2f row = {batch0, batch1} for one j; halves written by the 2 cvts.
#define UNPACK2V(dw, row, sfarr)                                              \
    sfarr[row]     = (v2f){(float)( (dw)        & 255u),                      \
                           (float)(((dw) >> 8)  & 255u)};                     \
    sfarr[(row)+1] = (v2f){(float)(((dw) >> 16) & 255u),                      \
                           (float)( (dw) >> 24)};

// 4 pk_fmas (= 8 MACs): weight component jj pairs with sf row jj
// (j ascending per component chain).
#define PKFMA8(accv, wv, sfarr, base)                                         \
    accv = __builtin_elementwise_fma(splat2(wv.x), sfarr[(base)+0], accv);    \
    accv = __builtin_elementwise_fma(splat2(wv.y), sfarr[(base)+1], accv);    \
    accv = __builtin_elementwise_fma(splat2(wv.z), sfarr[(base)+2], accv);    \
    accv = __builtin_elementwise_fma(splat2(wv.w), sfarr[(base)+3], accv);

// LDS-only drain; VMEM (x loads, out stores) stays in flight on purpose.
#define FENCE_LGKM() asm volatile("s_waitcnt lgkmcnt(0)" ::: "memory")

__global__ __launch_bounds__(BLOCK, 2)
void snn_pk(const float* __restrict__ x,
            const float* __restrict__ W1g, const float* __restrict__ b1g,
            const float* __restrict__ W2g, const float* __restrict__ b2g,
            const float* __restrict__ W3g, const float* __restrict__ b3g,
            float* __restrict__ out)
{
    // Chunk-major weights (measured conflict-free): cell (c,l) = 16 B.
    __shared__ __align__(16) float          W2L[36 * 64 * 4];      // 36864 B
    __shared__ __align__(16) float          W3L[18 * 64 * 4];      // 18432 B
    __shared__ __align__(16) float          W1L[96 * 12];          //  4608 B
    // Spikes, batch-packed ushorts; s1/s2 alias this buffer (R16-verified).
    __shared__ __align__(16) unsigned short spk[TC][WAVES][4][24]; //  3072 B
    // total 62,976 B -> 1 block/CU, 8 waves/CU = 2/SIMD.

    const int tid = threadIdx.x;
    const int w   = tid >> 6;     // wave 0..7
    const int l   = tid & 63;     // lane
    const int q   = l >> 2;       // quad 0..15
    const int r   = l & 3;        // residue lane
    const int r01 = r & 1;        // this lane's batch (0/1)
    const int bL  = l >> 5;       // L1 batch 0..1
    const int bg0 = blockIdx.x * NB + w * BPW;   // wave's batch base

    // ---- one-time weight staging (scattered; L2-cached) ----
    for (int idx = tid; idx < 36 * 64; idx += BLOCK) {
        const int c = idx >> 6, ll = idx & 63;
        const int s = c / 6, jq = c % 6, qq = ll >> 2, rr = ll & 3;
        #pragma unroll
        for (int jj = 0; jj < 4; ++jj)
            W2L[idx * 4 + jj] = W2g[(16 * s + qq) * H + 16 * jq + 4 * jj + rr];
    }
    for (int idx = tid; idx < 18 * 64; idx += BLOCK) {
        const int c = idx >> 6, ll = idx & 63;
        const int s = c / 6, jq = c % 6, qq = ll >> 2, rr = ll & 3;
        #pragma unroll
        for (int jj = 0; jj < 4; ++jj)
            W3L[idx * 4 + jj] = W3g[(16 * s + qq) * H + 16 * jq + 4 * jj + rr];
    }
    for (int idx = tid; idx < 96 * 12; idx += BLOCK) {
        const int n = idx / 12, k = idx % 12;
        W1L[idx] = (k < 9) ? W1g[n * D_INP + k] : 0.0f;
    }

    // ---- persistent register state: biases + membranes only ----
    float bb1[3], bb2[6], bb3[3];
    #pragma unroll
    for (int i = 0; i < 3; ++i) bb1[i] = b1g[(l & 31) + 32 * i];
    #pragma unroll
    for (int s = 0; s < 6; ++s) bb2[s] = b2g[16 * s + q];
    #pragma unroll
    for (int s = 0; s < 3; ++s) bb3[s] = b3g[16 * s + q];
    float m1[3] = {}, m2[6] = {}, m3[3] = {};

    float* out_spk = out;
    float* out_mem = out + (size_t)T_STEPS * BATCH * H3;

    __syncthreads();   // THE ONLY BLOCK BARRIER (weights visible)

    #pragma unroll 1
    for (int tc = 0; tc < T_STEPS; tc += TC) {
        // ---- x for 2 timesteps (broadcast loads) ----
        float xr[TC][D_INP];
        const float* xp = x + ((size_t)tc * BATCH + bg0 + bL) * D_INP;
        #pragma unroll
        for (int tp = 0; tp < TC; ++tp) {
            #pragma unroll
            for (int k = 0; k < D_INP; ++k)
                xr[tp][k] = xp[(size_t)tp * BATCH * D_INP + k];
        }

        // ---- layer 1 x2: P7 order verbatim, t-ascending (m1 recurrence) ----
        #pragma unroll
        for (int tp = 0; tp < TC; ++tp) {
            unsigned char* s1b = (unsigned char*)&spk[tp][w][0][0];
            #pragma unroll
            for (int i = 0; i < 3; ++i) {
                const int n1 = (l & 31) + 32 * i;
                const float4 wa = *(const float4*)&W1L[n1 * 12];
                const float4 wb = *(const float4*)&W1L[n1 * 12 + 4];
                const float  w8 = W1L[n1 * 12 + 8];
                const float q0 = __fmul_rn(wa.x, xr[tp][0]);   // exact
                const float q1 = __fmul_rn(wa.y, xr[tp][1]);
                const float q2 = __fmul_rn(wa.z, xr[tp][2]);
                const float q3 = __fmul_rn(wa.w, xr[tp][3]);
                const float q4 = __fmul_rn(wb.x, xr[tp][4]);
                const float q5 = __fmul_rn(wb.y, xr[tp][5]);
                const float q6 = __fmul_rn(wb.z, xr[tp][6]);
                const float q7 = __fmul_rn(wb.w, xr[tp][7]);
                const float q8 = __fmul_rn(w8,   xr[tp][8]);
                const float r0 = __fadd_rn(__fadd_rn(q8, q0), q4);  // tail-first
                const float r1 = __fadd_rn(q1, q5);
                const float r2 = __fadd_rn(q2, q6);
                const float r3 = __fadd_rn(q3, q7);
                const float s  = __fadd_rn(__fadd_rn(r0, r1), __fadd_rn(r2, r3));
                const float mn = lif_step(s, bb1[i], m1[i]);
                s1b[((n1 & 3) * 24 + (n1 >> 2)) * 2 + bL] =
                    (mn > 1.0f) ? (unsigned char)1 : (unsigned char)0;
            }
        }
        FENCE_LGKM();   // s1 writes land before the sweep reads

        // ---- ONE W2 sweep feeds both timesteps (packed over batches) ----
        v2f acc[TC][6] = {};
        #pragma unroll
        for (int jc = 0; jc < 3; ++jc) {
            const uint4 sp0 = *(const uint4*)&spk[0][w][r][8 * jc];
            const uint4 sp1 = *(const uint4*)&spk[1][w][r][8 * jc];
            v2f sf0[8], sf1[8];
            UNPACK2V(sp0.x, 0, sf0) UNPACK2V(sp0.y, 2, sf0)
            UNPACK2V(sp0.z, 4, sf0) UNPACK2V(sp0.w, 6, sf0)
            UNPACK2V(sp1.x, 0, sf1) UNPACK2V(sp1.y, 2, sf1)
            UNPACK2V(sp1.z, 4, sf1) UNPACK2V(sp1.w, 6, sf1)
            #pragma unroll
            for (int sh = 0; sh < 2; ++sh) {          // s-halves {0..2},{3..5}
                float4 wA[3], wB[3];
                #pragma unroll
                for (int si = 0; si < 3; ++si) {
                    const int s = 3 * sh + si;
                    wA[si] = *(const float4*)&W2L[((s * 6 + 2 * jc)     * 64 + l) * 4];
                    wB[si] = *(const float4*)&W2L[((s * 6 + 2 * jc + 1) * 64 + l) * 4];
                }
                #pragma unroll
                for (int si = 0; si < 3; ++si) {
                    PKFMA8(acc[0][3 * sh + si], wA[si], sf0, 0)
                    PKFMA8(acc[0][3 * sh + si], wB[si], sf0, 4)
                    PKFMA8(acc[1][3 * sh + si], wA[si], sf1, 0)
                    PKFMA8(acc[1][3 * sh + si], wB[si], sf1, 4)
                }
            }
        }
        FENCE_LGKM();   // WAR: all s1 reads done before s2 overwrites buffer

        // ---- LIF2 x2 (t-ascending per m2[s] chain) + s2 writes ----
        #pragma unroll
        for (int tp = 0; tp < TC; ++tp) {
            unsigned char* s2b = (unsigned char*)&spk[tp][w][0][0];
            #pragma unroll
            for (int s = 0; s < 6; ++s) {
                const float g0 = quad_red(acc[tp][s].x);   // (c0+c1)+(c2+c3)
                const float g1 = quad_red(acc[tp][s].y);
                const float sv = r01 ? g1 : g0;
                const float mn = lif_step(sv, bb2[s], m2[s]);   // batch r01
                if (r < 2) {
                    const int n2 = 16 * s + q;
                    s2b[((n2 & 3) * 24 + (n2 >> 2)) * 2 + r] =
                        (mn > 1.0f) ? (unsigned char)1 : (unsigned char)0;
                }
            }
        }
        FENCE_LGKM();   // s2 writes land before the L3 sweep reads

        // ---- ONE W3 sweep feeds both timesteps (packed over batches) ----
        v2f a3[TC][3] = {};
        #pragma unroll
        for (int jc = 0; jc < 3; ++jc) {
            const uint4 sp0 = *(const uint4*)&spk[0][w][r][8 * jc];
            const uint4 sp1 = *(const uint4*)&spk[1][w][r][8 * jc];
            v2f sf0[8], sf1[8];
            UNPACK2V(sp0.x, 0, sf0) UNPACK2V(sp0.y, 2, sf0)
            UNPACK2V(sp0.z, 4, sf0) UNPACK2V(sp0.w, 6, sf0)
            UNPACK2V(sp1.x, 0, sf1) UNPACK2V(sp1.y, 2, sf1)
            UNPACK2V(sp1.z, 4, sf1) UNPACK2V(sp1.w, 6, sf1)
            float4 wA[3], wB[3];
            #pragma unroll
            for (int s = 0; s < 3; ++s) {
                wA[s] = *(const float4*)&W3L[((s * 6 + 2 * jc)     * 64 + l) * 4];
                wB[s] = *(const float4*)&W3L[((s * 6 + 2 * jc + 1) * 64 + l) * 4];
            }
            #pragma unroll
            for (int s = 0; s < 3; ++s) {
                PKFMA8(a3[0][s], wA[s], sf0, 0)
                PKFMA8(a3[0][s], wB[s], sf0, 4)
                PKFMA8(a3[1][s], wA[s], sf1, 0)
                PKFMA8(a3[1][s], wB[s], sf1, 4)
            }
        }

        // ---- LIF3 x2 + stores (t-ascending per m3[s] chain) ----
        #pragma unroll
        for (int tp = 0; tp < TC; ++tp) {
            #pragma unroll
            for (int s = 0; s < 3; ++s) {
                const float g0 = quad_red(a3[tp][s].x);
                const float g1 = quad_red(a3[tp][s].y);
                const float sv = r01 ? g1 : g0;
                const float mn = lif_step(sv, bb3[s], m3[s]);   // batch r01
                if (r < 2) {
                    const size_t ob =
                        ((size_t)(tc + tp) * BATCH + bg0 + r) * H3 + 16 * s + q;
                    out_spk[ob] = (mn > 1.0f) ? 1.0f : 0.0f;
                    out_mem[ob] = mn;
                }
            }
        }
        FENCE_LGKM();   // WAR: L3's s2 reads done before next chunk's L1 writes
    }
}

extern "C" void kernel_launch(void* const* d_in, const int* in_sizes, int n_in,
                              void* d_out, int out_size, void* d_ws, size_t ws_size,
                              hipStream_t stream)
{
    const float* x  = (const float*)d_in[0];
    const float* W1 = (const float*)d_in[1];
    const float* b1 = (const float*)d_in[2];
    const float* W2 = (const float*)d_in[3];
    const float* b2 = (const float*)d_in[4];
    const float* W3 = (const float*)d_in[5];
    const float* b3 = (const float*)d_in[6];
    float* out = (float*)d_out;

    snn_pk<<<dim3(NBLK), dim3(BLOCK), 0, stream>>>(
        x, W1, b1, W2, b2, W3, b3, out);
}

// Round 11
// 409.544 us; speedup vs baseline: 1.1024x; 1.1024x over previous
//
#include <hip/hip_runtime.h>

// DeepSNNController: 3-layer LIF SNN, T=100, B=4096, 9 -> 96 -> 96 -> 48.
//
// R19 = R17 (TC=2 time-chunked, 293us, absmax=0) upgraded to TC=4 with the
// register-feasible structure R16 lacked. R18 post-mortem: v2f packing
// regressed (scalarized splats + even-pair regalloc at the 128 cap) ->
// reverted. R16 post-mortem: TC=4 with full acc[4][6][2]=48 spilled.
// This round: TC=4 via S-HALF-SPLIT:
//   * W2 sweep runs twice over s-halves {0..2}, {3..5}: live acc is
//     acc[4][3][2]=24 regs; weight-read COUNT is conserved by the split
//     (each half reads only its own chunk-major cells).
//   * LIF2(half) runs between half-sweeps, REGISTER-ONLY (spike bits pack
//     into one uint); s2 byte-writes are DEFERRED until after a fence
//     confirms all s1 reads done -> s1/s2 aliasing (R16-verified) is safe.
//   * W1 compacted to 3 arrays (3456B) so LDS = 64,896 <= 64KB envelope.
// Weight ds_read_b128: 27 -> 13.5 per wave/t (216 -> 108 per CU/t, ~-1.3k
// cyc on the LDS pipe); cost: spikes re-unpacked per half (+48 cvt/lane/t).
//
// Exactness (absmax must stay 0): every (tp, s, batch) accumulator chain
// keeps the exact R14/R16/R17 j-ascending fmaf order (jc outer asc; within
// jc: wA j=8jc..+3 then wB j=8jc+4..+7); the s-half split only reorders
// ACROSS independent chains. Combine (c0+c1)+(c2+c3) via quad-perm DPP
// exchange-adds; K=9 L1 tail-first r0=(q8+q0)+q4 verbatim; LIF pinned
// mn=((0.92*mp)+(dot+b))-reset, tp-ascending per membrane chain (each
// m2[s]/m3[s] chain updated in t order). Deferred s2 writes change only
// WHEN bytes are stored, not their values. Products exact (spikes {0,1}).
//
// Structure (unchanged): wave-autonomous, zero barriers in t-loop, 8 waves
// x 2 batches, grid 256 = 1 block/CU = 2 waves/SIMD; chunk-major 16B weight
// cells (measured conflict-free); fences lgkmcnt-only (x loads / out stores
// stay in flight). T=100 = 25 chunks of TC=4.

constexpr int T_STEPS = 100;
constexpr int BATCH   = 4096;
constexpr int D_INP   = 9;
constexpr int H       = 96;
constexpr int H3      = 48;
constexpr int WAVES   = 8;
constexpr int BPW     = 2;               // batches per wave
constexpr int NB      = WAVES * BPW;     // 16 batches per block
constexpr int BLOCK   = WAVES * 64;      // 512 threads
constexpr int NBLK    = BATCH / NB;      // 256 blocks = 1 per CU
constexpr int TC      = 4;               // timesteps per weight sweep

__device__ __forceinline__ float lif_step(float sum, float bias, float& m) {
    const float cur   = __fadd_rn(sum, bias);
    const float mp    = m;
    const float reset = (mp > 1.0f) ? 1.0f : 0.0f;
    const float mn    = __fsub_rn(__fadd_rn(__fmul_rn(0.92f, mp), cur), reset);
    m = mn;
    return mn;
}

#if defined(__has_builtin)
#if __has_builtin(__builtin_amdgcn_mov_dpp)
#define SNN_HAS_DPP 1
#endif
#endif

// Quad exchange-and-add. CTRL=0xB1: quad_perm [1,0,3,2] (xor 1);
// CTRL=0x4E: quad_perm [2,3,0,1] (xor 2).
template <int CTRL>
__device__ __forceinline__ float xadd(float c) {
#ifdef SNN_HAS_DPP
    const int o = __builtin_amdgcn_mov_dpp(__float_as_int(c), CTRL, 0xF, 0xF, false);
    return __fadd_rn(c, __int_as_float(o));
#else
    return __fadd_rn(c, __shfl_xor(c, (CTRL == 0xB1) ? 1 : 2, 64));
#endif
}

// lanes r=0..3 hold P7 residue partials c_r; returns (c0+c1)+(c2+c3) in ALL lanes.
__device__ __forceinline__ float quad_red(float c) {
    return xadd<0x4E>(xadd<0xB1>(c));
}

// dword = ushorts {j0, j0+1}: bytes [b0(j0), b1(j0), b0(j0+1), b1(j0+1)].
#define UNPACK2S(dw, row, sfarr)                                              \
    sfarr[row][0]     = (float)( (dw)        & 255u);                         \
    sfarr[row][1]     = (float)(((dw) >> 8)  & 255u);                         \
    sfarr[(row)+1][0] = (float)(((dw) >> 16) & 255u);                         \
    sfarr[(row)+1][1] = (float)( (dw) >> 24);

// 8 fmas: weight component jj pairs with sf row jj (j ascending per chain).
#define FMA8S(accv, wv, sfarr, base)                                          \
    accv[0] = fmaf(wv.x, sfarr[(base)+0][0], accv[0]);                        \
    accv[1] = fmaf(wv.x, sfarr[(base)+0][1], accv[1]);                        \
    accv[0] = fmaf(wv.y, sfarr[(base)+1][0], accv[0]);                        \
    accv[1] = fmaf(wv.y, sfarr[(base)+1][1], accv[1]);                        \
    accv[0] = fmaf(wv.z, sfarr[(base)+2][0], accv[0]);                        \
    accv[1] = fmaf(wv.z, sfarr[(base)+2][1], accv[1]);                        \
    accv[0] = fmaf(wv.w, sfarr[(base)+3][0], accv[0]);                        \
    accv[1] = fmaf(wv.w, sfarr[(base)+3][1], accv[1]);

// LDS-only drain; VMEM (x loads, out stores) stays in flight on purpose.
#define FENCE_LGKM() asm volatile("s_waitcnt lgkmcnt(0)" ::: "memory")

__global__ __launch_bounds__(BLOCK, 2)
void snn_t4(const float* __restrict__ x,
            const float* __restrict__ W1g, const float* __restrict__ b1g,
            const float* __restrict__ W2g, const float* __restrict__ b2g,
            const float* __restrict__ W3g, const float* __restrict__ b3g,
            float* __restrict__ out)
{
    // Chunk-major weights (measured conflict-free): cell (c,l) = 16 B.
    __shared__ __align__(16) float          W2L[36 * 64 * 4];      // 36864 B
    __shared__ __align__(16) float          W3L[18 * 64 * 4];      // 18432 B
    __shared__ __align__(16) float4         W1a[96];               //  1536 B
    __shared__ __align__(16) float4         W1b[96];               //  1536 B
    __shared__ __align__(16) float          W1c[96];               //   384 B
    // Spikes, batch-packed ushorts; s1/s2 alias (writes DEFERRED past reads).
    __shared__ __align__(16) unsigned short spk[TC][WAVES][4][24]; //  6144 B
    // total 64,896 B -> 1 block/CU, 8 waves/CU = 2/SIMD.

    const int tid = threadIdx.x;
    const int w   = tid >> 6;     // wave 0..7
    const int l   = tid & 63;     // lane
    const int q   = l >> 2;       // quad 0..15
    const int r   = l & 3;        // residue lane
    const int r01 = r & 1;        // this lane's batch (0/1)
    const int bL  = l >> 5;       // L1 batch 0..1
    const int bg0 = blockIdx.x * NB + w * BPW;   // wave's batch base

    // ---- one-time weight staging (scattered; L2-cached) ----
    for (int idx = tid; idx < 36 * 64; idx += BLOCK) {
        const int c = idx >> 6, ll = idx & 63;
        const int s = c / 6, jq = c % 6, qq = ll >> 2, rr = ll & 3;
        #pragma unroll
        for (int jj = 0; jj < 4; ++jj)
            W2L[idx * 4 + jj] = W2g[(16 * s + qq) * H + 16 * jq + 4 * jj + rr];
    }
    for (int idx = tid; idx < 18 * 64; idx += BLOCK) {
        const int c = idx >> 6, ll = idx & 63;
        const int s = c / 6, jq = c % 6, qq = ll >> 2, rr = ll & 3;
        #pragma unroll
        for (int jj = 0; jj < 4; ++jj)
            W3L[idx * 4 + jj] = W3g[(16 * s + qq) * H + 16 * jq + 4 * jj + rr];
    }
    if (tid < 96) {
        const int n = tid;
        W1a[n] = make_float4(W1g[n * 9 + 0], W1g[n * 9 + 1],
                             W1g[n * 9 + 2], W1g[n * 9 + 3]);
        W1b[n] = make_float4(W1g[n * 9 + 4], W1g[n * 9 + 5],
                             W1g[n * 9 + 6], W1g[n * 9 + 7]);
        W1c[n] = W1g[n * 9 + 8];
    }

    // ---- persistent register state: biases + membranes only ----
    float bb1[3], bb2[6], bb3[3];
    #pragma unroll
    for (int i = 0; i < 3; ++i) bb1[i] = b1g[(l & 31) + 32 * i];
    #pragma unroll
    for (int s = 0; s < 6; ++s) bb2[s] = b2g[16 * s + q];
    #pragma unroll
    for (int s = 0; s < 3; ++s) bb3[s] = b3g[16 * s + q];
    float m1[3] = {}, m2[6] = {}, m3[3] = {};

    float* out_spk = out;
    float* out_mem = out + (size_t)T_STEPS * BATCH * H3;

    __syncthreads();   // THE ONLY BLOCK BARRIER (weights visible)

    #pragma unroll 1
    for (int tc = 0; tc < T_STEPS; tc += TC) {
        // ---- x for 4 timesteps (broadcast loads; xr dead after L1) ----
        float xr[TC][D_INP];
        const float* xp = x + ((size_t)tc * BATCH + bg0 + bL) * D_INP;
        #pragma unroll
        for (int tp = 0; tp < TC; ++tp) {
            #pragma unroll
            for (int k = 0; k < D_INP; ++k)
                xr[tp][k] = xp[(size_t)tp * BATCH * D_INP + k];
        }

        // ---- layer 1 x4: P7 order verbatim, t-ascending (m1 recurrence) ----
        #pragma unroll
        for (int tp = 0; tp < TC; ++tp) {
            unsigned char* s1b = (unsigned char*)&spk[tp][w][0][0];
            #pragma unroll
            for (int i = 0; i < 3; ++i) {
                const int n1 = (l & 31) + 32 * i;
                const float4 wa = W1a[n1];
                const float4 wb = W1b[n1];
                const float  w8 = W1c[n1];
                const float q0 = __fmul_rn(wa.x, xr[tp][0]);   // exact
                const float q1 = __fmul_rn(wa.y, xr[tp][1]);
                const float q2 = __fmul_rn(wa.z, xr[tp][2]);
                const float q3 = __fmul_rn(wa.w, xr[tp][3]);
                const float q4 = __fmul_rn(wb.x, xr[tp][4]);
                const float q5 = __fmul_rn(wb.y, xr[tp][5]);
                const float q6 = __fmul_rn(wb.z, xr[tp][6]);
                const float q7 = __fmul_rn(wb.w, xr[tp][7]);
                const float q8 = __fmul_rn(w8,   xr[tp][8]);
                const float r0 = __fadd_rn(__fadd_rn(q8, q0), q4);  // tail-first
                const float r1 = __fadd_rn(q1, q5);
                const float r2 = __fadd_rn(q2, q6);
                const float r3 = __fadd_rn(q3, q7);
                const float s  = __fadd_rn(__fadd_rn(r0, r1), __fadd_rn(r2, r3));
                const float mn = lif_step(s, bb1[i], m1[i]);
                s1b[((n1 & 3) * 24 + (n1 >> 2)) * 2 + bL] =
                    (mn > 1.0f) ? (unsigned char)1 : (unsigned char)0;
            }
        }
        FENCE_LGKM();   // s1 writes land before the sweeps read

        unsigned sbits = 0u;   // deferred s2 spike bits: bit (tp*6 + s)

        // ---- W2 sweep, s-half 0 (s = 0..2): one weight read, 4 timesteps ----
        {
            float acc[TC][3][2] = {};
            #pragma unroll
            for (int jc = 0; jc < 3; ++jc) {
                float4 wA[3], wB[3];
                #pragma unroll
                for (int si = 0; si < 3; ++si) {
                    wA[si] = *(const float4*)&W2L[((si * 6 + 2 * jc)     * 64 + l) * 4];
                    wB[si] = *(const float4*)&W2L[((si * 6 + 2 * jc + 1) * 64 + l) * 4];
                }
                #pragma unroll
                for (int tp = 0; tp < TC; ++tp) {
                    const uint4 sp = *(const uint4*)&spk[tp][w][r][8 * jc];
                    float sf[8][2];
                    UNPACK2S(sp.x, 0, sf) UNPACK2S(sp.y, 2, sf)
                    UNPACK2S(sp.z, 4, sf) UNPACK2S(sp.w, 6, sf)
                    #pragma unroll
                    for (int si = 0; si < 3; ++si) {
                        FMA8S(acc[tp][si], wA[si], sf, 0)
                        FMA8S(acc[tp][si], wB[si], sf, 4)
                    }
                }
            }
            // LIF2 half 0 (register-only; tp-ascending per m2[s] chain)
            #pragma unroll
            for (int tp = 0; tp < TC; ++tp) {
                #pragma unroll
                for (int si = 0; si < 3; ++si) {
                    const float g0 = quad_red(acc[tp][si][0]);   // (c0+c1)+(c2+c3)
                    const float g1 = quad_red(acc[tp][si][1]);
                    const float sv = r01 ? g1 : g0;
                    const float mn = lif_step(sv, bb2[si], m2[si]);   // batch r01
                    sbits |= (mn > 1.0f) ? (1u << (tp * 6 + si)) : 0u;
                }
            }
        }

        // ---- W2 sweep, s-half 1 (s = 3..5); s1 still intact (no writes yet) ----
        {
            float acc[TC][3][2] = {};
            #pragma unroll
            for (int jc = 0; jc < 3; ++jc) {
                float4 wA[3], wB[3];
                #pragma unroll
                for (int si = 0; si < 3; ++si) {
                    const int s = 3 + si;
                    wA[si] = *(const float4*)&W2L[((s * 6 + 2 * jc)     * 64 + l) * 4];
                    wB[si] = *(const float4*)&W2L[((s * 6 + 2 * jc + 1) * 64 + l) * 4];
                }
                #pragma unroll
                for (int tp = 0; tp < TC; ++tp) {
                    const uint4 sp = *(const uint4*)&spk[tp][w][r][8 * jc];
                    float sf[8][2];
                    UNPACK2S(sp.x, 0, sf) UNPACK2S(sp.y, 2, sf)
                    UNPACK2S(sp.z, 4, sf) UNPACK2S(sp.w, 6, sf)
                    #pragma unroll
                    for (int si = 0; si < 3; ++si) {
                        FMA8S(acc[tp][si], wA[si], sf, 0)
                        FMA8S(acc[tp][si], wB[si], sf, 4)
                    }
                }
            }
            // LIF2 half 1 (tp-ascending per m2[3+si] chain)
            #pragma unroll
            for (int tp = 0; tp < TC; ++tp) {
                #pragma unroll
                for (int si = 0; si < 3; ++si) {
                    const float g0 = quad_red(acc[tp][si][0]);
                    const float g1 = quad_red(acc[tp][si][1]);
                    const float sv = r01 ? g1 : g0;
                    const float mn = lif_step(sv, bb2[3 + si], m2[3 + si]);
                    sbits |= (mn > 1.0f) ? (1u << (tp * 6 + 3 + si)) : 0u;
                }
            }
        }
        FENCE_LGKM();   // ALL s1 reads retired -> safe to overwrite with s2

        // ---- deferred s2 writes (aliased buffer; values == R17's) ----
        #pragma unroll
        for (int tp = 0; tp < TC; ++tp) {
            unsigned char* s2b = (unsigned char*)&spk[tp][w][0][0];
            #pragma unroll
            for (int s = 0; s < 6; ++s) {
                if (r < 2) {
                    // n2 = 16s+q: n2&3 = q&3, n2>>2 = 4s + (q>>2)
                    s2b[((q & 3) * 24 + 4 * s + (q >> 2)) * 2 + r] =
                        (unsigned char)((sbits >> (tp * 6 + s)) & 1u);
                }
            }
        }
        FENCE_LGKM();   // s2 writes land before the W3 sweep reads

        // ---- ONE W3 sweep feeds all 4 timesteps ----
        float a3[TC][3][2] = {};
        #pragma unroll
        for (int jc = 0; jc < 3; ++jc) {
            float4 wA[3], wB[3];
            #pragma unroll
            for (int s = 0; s < 3; ++s) {
                wA[s] = *(const float4*)&W3L[((s * 6 + 2 * jc)     * 64 + l) * 4];
                wB[s] = *(const float4*)&W3L[((s * 6 + 2 * jc + 1) * 64 + l) * 4];
            }
            #pragma unroll
            for (int tp = 0; tp < TC; ++tp) {
                const uint4 sp = *(const uint4*)&spk[tp][w][r][8 * jc];
                float sf[8][2];
                UNPACK2S(sp.x, 0, sf) UNPACK2S(sp.y, 2, sf)
                UNPACK2S(sp.z, 4, sf) UNPACK2S(sp.w, 6, sf)
                #pragma unroll
                for (int s = 0; s < 3; ++s) {
                    FMA8S(a3[tp][s], wA[s], sf, 0)
                    FMA8S(a3[tp][s], wB[s], sf, 4)
                }
            }
        }

        // ---- LIF3 x4 + stores (tp-ascending per m3[s] chain) ----
        #pragma unroll
        for (int tp = 0; tp < TC; ++tp) {
            #pragma unroll
            for (int s = 0; s < 3; ++s) {
                const float g0 = quad_red(a3[tp][s][0]);
                const float g1 = quad_red(a3[tp][s][1]);
                const float sv = r01 ? g1 : g0;
                const float mn = lif_step(sv, bb3[s], m3[s]);   // batch r01
                if (r < 2) {
                    const size_t ob =
                        ((size_t)(tc + tp) * BATCH + bg0 + r) * H3 + 16 * s + q;
                    out_spk[ob] = (mn > 1.0f) ? 1.0f : 0.0f;
                    out_mem[ob] = mn;
                }
            }
        }
        FENCE_LGKM();   // WAR: W3's s2 reads done before next chunk's L1 writes
    }
}

extern "C" void kernel_launch(void* const* d_in, const int* in_sizes, int n_in,
                              void* d_out, int out_size, void* d_ws, size_t ws_size,
                              hipStream_t stream)
{
    const float* x  = (const float*)d_in[0];
    const float* W1 = (const float*)d_in[1];
    const float* b1 = (const float*)d_in[2];
    const float* W2 = (const float*)d_in[3];
    const float* b2 = (const float*)d_in[4];
    const float* W3 = (const float*)d_in[5];
    const float* b3 = (const float*)d_in[6];
    float* out = (float*)d_out;

    snn_t4<<<dim3(NBLK), dim3(BLOCK), 0, stream>>>(
        x, W1, b1, W2, b2, W3, b3, out);
}